// Round 5
// baseline (503.414 us; speedup 1.0000x reference)
//
#include <hip/hip_runtime.h>

#define SEQ     8192
#define DM      1024
#define DS      64
#define DI      128
#define NIT     50
#define NTHR    512
#define WIN     2       // truncated lookback window

// bf16 LDS strides, dword-stride == 5 mod 32 (2-way max on frag reads, free)
#define ZH_STR  202     // [z:128 | h:64] + 10
#define XS_STR  1034    // 1024 + 10

// ---------------- v2: 512 blocks x 16-token chunks (2 blocks/CU) ----------------
#define NBLK2   512
#define CHUNK2  16
#define RING2   4
#define LAG2    2
#define CSTR2   16      // cons stride in ints (64 B) -> 512*64B = 32 KB
// v2 LDS map (57,664 B -> 2 blocks/CU):
//   region [0, 33088) time-multiplexed: phase1 xs 16*1034*2; phase3 zhA/zhB 2*6464
#define V2_OFF_ZHA  0
#define V2_OFF_ZHB  6464
#define V2_OFF_XS   0
#define V2_OFF_LAM  33088               // 16*64*4 = 4096
#define V2_OFF_U    37184               // 4096
#define V2_OFF_XLAM 41280               // 4096
#define V2_OFF_XU   45376               // 4096
#define V2_OFF_XF   49472               // 16*128*4 = 8192
#define V2_LDS      57664

// ---------------- v1 (fallback, round-3-proven): 256 blocks x 32-token chunks ----
#define NBLK1   256
#define CHUNK1  32
#define RING1   8
#define LAG1    6
#define W1_STR  138
#define W2_STR  202
#define V1_OFF_W1   0
#define V1_OFF_W2   35328
#define V1_OFF_ZHA  0
#define V1_OFF_ZHB  12928
#define V1_OFF_XS   0
#define V1_OFF_LAM  87040
#define V1_OFF_U    95232
#define V1_OFF_XLAM 103424
#define V1_OFF_XU   111616
#define V1_OFF_XF   119808
#define V1_LDS      136192

typedef __attribute__((ext_vector_type(8))) short short8;
typedef __attribute__((ext_vector_type(4))) float floatx4;
typedef unsigned long long u64;

__device__ __forceinline__ unsigned short f2b(float f) {
    unsigned int u = __float_as_uint(f);
    u += 0x7fffu + ((u >> 16) & 1u);          // RNE
    return (unsigned short)(u >> 16);
}
__device__ __forceinline__ float sigmoidf_(float v) { return 1.f / (1.f + __expf(-v)); }

// wait vmcnt(0) ONLY — drains this wave's outstanding global ops to the
// coherent point with ZERO cache maintenance.
__device__ __forceinline__ void drain_vm() {
    asm volatile("" ::: "memory");
    __builtin_amdgcn_s_waitcnt(0x0F70);
    asm volatile("" ::: "memory");
}

union VS { struct { float v; int st; } p; u64 u; };   // tagged value (8B atomic)

// =======================================================================
// v2: CHUNK=16, NBLK=512, weights-in-registers, 2 blocks/CU occupancy.
// aggv layout: [RING2][NBLK2][DS][2] u64 (2 MB); cons at +2MB, 64B stride.
// =======================================================================
__global__ __launch_bounds__(NTHR, 4)
void implicit_v2(const float* __restrict__ x,
                 const float* __restrict__ f_w,   const float* __restrict__ f_b,
                 const float* __restrict__ lam_w, const float* __restrict__ lam_b,
                 const float* __restrict__ u_w,   const float* __restrict__ u_b,
                 const float* __restrict__ out_w, const float* __restrict__ out_b,
                 float* __restrict__ out,         u64* __restrict__ aggv,
                 int* __restrict__ cons)
{
    extern __shared__ unsigned char smem_raw[];
    unsigned short* zhA = (unsigned short*)(smem_raw + V2_OFF_ZHA);
    unsigned short* zhB = (unsigned short*)(smem_raw + V2_OFF_ZHB);
    unsigned short* xs  = (unsigned short*)(smem_raw + V2_OFF_XS);
    float* lamL = (float*)(smem_raw + V2_OFF_LAM);
    float* uL   = (float*)(smem_raw + V2_OFF_U);
    float* xlam = (float*)(smem_raw + V2_OFF_XLAM);
    float* xu   = (float*)(smem_raw + V2_OFF_XU);
    float* xf   = (float*)(smem_raw + V2_OFF_XF);

    const int b    = blockIdx.x;
    const int tid  = threadIdx.x;
    const int wid  = tid >> 6;
    const int lane = tid & 63;
    const int l15  = lane & 15;
    const int lg   = lane >> 4;
    const int t0   = b * CHUNK2;

    // ---------------- phase 1: stage x chunk as bf16 ----------------
    for (int i = tid; i < CHUNK2 * DM; i += NTHR) {
        int t = i >> 10, k = i & (DM - 1);
        xs[t * XS_STR + k] = f2b(x[(size_t)(t0 + t) * DM + k]);
    }
    __syncthreads();

    // xpre = x @ [lam_wx|u_wx|f_wx]^T + bias via MFMA (N=256)
    for (int half = 0; half < 2; ++half) {
        int nt = wid + 8 * half;
        int n  = nt * 16 + l15;              // 0..255
        const float* wrow; float bias;
        if (n < 64)       { wrow = lam_w + (size_t)n        * (DI + DM) + DI;             bias = lam_b[n]; }
        else if (n < 128) { wrow = u_w   + (size_t)(n - 64) * (DI + DM) + DI;             bias = u_b[n - 64]; }
        else              { wrow = f_w   + (size_t)(n - 128) * (DI + DS + DM) + (DI + DS); bias = f_b[n - 128]; }

        floatx4 acc = {0.f, 0.f, 0.f, 0.f};
        for (int kk = 0; kk < DM / 32; ++kk) {
            const float* wp = wrow + kk * 32 + lg * 8;
            short8 bf;
            #pragma unroll
            for (int j = 0; j < 8; ++j) bf[j] = (short)f2b(wp[j]);
            const short8 af = *(const short8*)(xs + l15 * XS_STR + kk * 32 + lg * 8);
            acc = __builtin_amdgcn_mfma_f32_16x16x32_bf16(af, bf, acc, 0, 0, 0);
        }
        #pragma unroll
        for (int r = 0; r < 4; ++r) {
            int t = lg * 4 + r;              // 0..15
            float v = acc[r] + bias;
            if (n < 64)       xlam[t * DS + n] = v;
            else if (n < 128) xu[t * DS + (n - 64)] = v;
            else              xf[t * DI + (n - 128)] = v;
        }
    }
    __syncthreads();   // done reading xs

    // ---------------- phase 2: hoist stationary B fragments direct from global
    short8 w1f[4], w2f[6];
    {
        const int n = wid * 16 + l15;        // 0..127
        const float* r1 = (n < 64) ? lam_w + (size_t)n * (DI + DM)
                                   : u_w   + (size_t)(n - 64) * (DI + DM);
        #pragma unroll
        for (int kk = 0; kk < 4; ++kk) {
            const float* wp = r1 + kk * 32 + lg * 8;
            #pragma unroll
            for (int j = 0; j < 8; ++j) w1f[kk][j] = (short)f2b(wp[j]);
        }
        const float* r2 = f_w + (size_t)n * (DI + DS + DM);
        #pragma unroll
        for (int kk = 0; kk < 6; ++kk) {
            const float* wp = r2 + kk * 32 + lg * 8;
            #pragma unroll
            for (int j = 0; j < 8; ++j) w2f[kk][j] = (short)f2b(wp[j]);
        }
    }
    for (int i = tid; i < 2 * CHUNK2 * ZH_STR; i += NTHR) zhA[i] = 0;   // z0 = 0 (both bufs)
    __syncthreads();

    // ---------------- fixed-point iterations (3 barriers/iter) ----------------
    for (int it = 0; it < NIT; ++it) {
        const int slot = it & (RING2 - 1);
        unsigned short* cur = (it & 1) ? zhB : zhA;
        unsigned short* nxt = (it & 1) ? zhA : zhB;

        // pre-issue coherent-point loads; latency hides under GEMM1.
        u64 pa0 = 0, pa1 = 0, pb0 = 0, pb1 = 0;
        int  cpre = 0x7fffffff;
        const u64 *l1 = 0, *l2 = 0;
        if (wid == 1 && b >= 1 && it >= LAG2) {
            const int pslot = (it - LAG2) & (RING2 - 1);
            l1 = aggv + (((size_t)pslot * NBLK2 + (b - 1)) * DS + lane) * 2;
            pa0 = __hip_atomic_load(&l1[0], __ATOMIC_RELAXED, __HIP_MEMORY_SCOPE_AGENT);
            pa1 = __hip_atomic_load(&l1[1], __ATOMIC_RELAXED, __HIP_MEMORY_SCOPE_AGENT);
            if (b >= 2) {
                l2 = aggv + (((size_t)pslot * NBLK2 + (b - 2)) * DS + lane) * 2;
                pb0 = __hip_atomic_load(&l2[0], __ATOMIC_RELAXED, __HIP_MEMORY_SCOPE_AGENT);
                pb1 = __hip_atomic_load(&l2[1], __ATOMIC_RELAXED, __HIP_MEMORY_SCOPE_AGENT);
            }
        }
        if (wid == 0 && it >= RING2 && lane < WIN && (b + 1 + lane) < NBLK2)
            cpre = __hip_atomic_load(&cons[(b + 1 + lane) * CSTR2],
                                     __ATOMIC_RELAXED, __HIP_MEMORY_SCOPE_AGENT);

        // stage a: GEMM1  z @ W1^T -> lam | u
        {
            floatx4 acc = {0.f, 0.f, 0.f, 0.f};
            #pragma unroll
            for (int kk = 0; kk < 4; ++kk) {
                const short8 af = *(const short8*)(cur + l15 * ZH_STR + kk*32 + lg*8);
                acc = __builtin_amdgcn_mfma_f32_16x16x32_bf16(af, w1f[kk], acc, 0, 0, 0);
            }
            const int n = wid * 16 + l15;
            #pragma unroll
            for (int r = 0; r < 4; ++r) {
                int t = lg * 4 + r;
                if (n < 64) lamL[t*DS + n] = sigmoidf_(acc[r] + xlam[t*DS + n]);
                else        uL[t*DS + (n - 64)] = acc[r] + xu[t*DS + (n - 64)];
            }
        }
        __syncthreads();

        // stage bc: wave0 = scan + WAR gate + tagged publish; wave1 = stamp-check
        // prefetched lagged lines + h-rescan + cons flag; then ALL waves GEMM2 z-part.
        floatx4 acc2 = {0.f, 0.f, 0.f, 0.f};
        if (wid == 0) {
            float L = 1.f, H = 0.f;
            #pragma unroll
            for (int t = 0; t < CHUNK2; ++t) {
                float lv = lamL[t*DS + lane], uv = uL[t*DS + lane];
                H = fmaf(lv, H, uv);
                L *= lv;
            }
            if (it >= RING2 && lane < WIN) {
                int j = b + 1 + lane;
                if (j < NBLK2) {
                    const int thr = it - RING2 + LAG2 + 1;
                    while (cpre < thr) {
                        __builtin_amdgcn_s_sleep(1);
                        cpre = __hip_atomic_load(&cons[j * CSTR2], __ATOMIC_RELAXED,
                                                 __HIP_MEMORY_SCOPE_AGENT);
                    }
                }
            }
            u64* line = aggv + (((size_t)slot * NBLK2 + b) * DS + lane) * 2;
            VS vL, vH;
            vL.p.v = L; vL.p.st = it + 1;
            vH.p.v = H; vH.p.st = it + 1;
            __hip_atomic_store(&line[0], vL.u, __ATOMIC_RELAXED, __HIP_MEMORY_SCOPE_AGENT);
            __hip_atomic_store(&line[1], vH.u, __ATOMIC_RELAXED, __HIP_MEMORY_SCOPE_AGENT);
        } else if (wid == 1) {
            float h = 0.f;
            if (b >= 1 && it >= LAG2) {
                const int est = it - LAG2 + 1;       // expected stamp
                VS aL, aH, bH;
                aL.u = pa0; aH.u = pa1; bH.u = pb1;
                bool ok = (aL.p.st == est) && (aH.p.st == est);
                if (b >= 2) { VS bL; bL.u = pb0;
                              ok = ok && (bL.p.st == est) && (bH.p.st == est); }
                while (!ok) {
                    __builtin_amdgcn_s_sleep(1);
                    aL.u = __hip_atomic_load(&l1[0], __ATOMIC_RELAXED, __HIP_MEMORY_SCOPE_AGENT);
                    aH.u = __hip_atomic_load(&l1[1], __ATOMIC_RELAXED, __HIP_MEMORY_SCOPE_AGENT);
                    ok = (aL.p.st == est) && (aH.p.st == est);
                    if (b >= 2) {
                        VS bL;
                        bL.u = __hip_atomic_load(&l2[0], __ATOMIC_RELAXED, __HIP_MEMORY_SCOPE_AGENT);
                        bH.u = __hip_atomic_load(&l2[1], __ATOMIC_RELAXED, __HIP_MEMORY_SCOPE_AGENT);
                        ok = ok && (bL.p.st == est) && (bH.p.st == est);
                    }
                }
                h = aH.p.v;
                if (b >= 2) h = fmaf(aL.p.v, bH.p.v, h);   // H_{b-1} + L_{b-1}*H_{b-2}
            }
            #pragma unroll
            for (int t = 0; t < CHUNK2; ++t) {
                cur[t * ZH_STR + DI + lane] = f2b(h);
                h = fmaf(lamL[t*DS + lane], h, uL[t*DS + lane]);
            }
            drain_vm();   // neighbor-line loads retired before declaring consumed
            if (lane == 0)
                __hip_atomic_store(&cons[b * CSTR2], it + 1,
                                   __ATOMIC_RELAXED, __HIP_MEMORY_SCOPE_AGENT);
        }
        #pragma unroll
        for (int kk = 0; kk < 4; ++kk) {     // GEMM2 z-part, all waves
            const short8 af = *(const short8*)(cur + l15 * ZH_STR + kk*32 + lg*8);
            acc2 = __builtin_amdgcn_mfma_f32_16x16x32_bf16(af, w2f[kk], acc2, 0, 0, 0);
        }
        __syncthreads();

        // stage d: h-part + silu -> nxt
        #pragma unroll
        for (int kk = 4; kk < 6; ++kk) {
            const short8 af = *(const short8*)(cur + l15 * ZH_STR + kk*32 + lg*8);
            acc2 = __builtin_amdgcn_mfma_f32_16x16x32_bf16(af, w2f[kk], acc2, 0, 0, 0);
        }
        {
            const int d = wid * 16 + l15;
            #pragma unroll
            for (int r = 0; r < 4; ++r) {
                int t = lg * 4 + r;
                float v = acc2[r] + xf[t*DI + d];
                nxt[t * ZH_STR + d] = f2b(v * sigmoidf_(v));   // silu; dt=1
            }
        }
        __syncthreads();
    }

    // ---------------- out = z @ out_w^T + out_b ----------------
    unsigned short* zfin = (NIT & 1) ? zhB : zhA;
    for (int q = 0; q < 8; ++q) {
        int nt = wid * 8 + q;
        int n  = nt * 16 + l15;              // 0..1023
        float bias = out_b[n];
        floatx4 acc = {0.f, 0.f, 0.f, 0.f};
        #pragma unroll
        for (int kk = 0; kk < 4; ++kk) {
            const float* wp = out_w + (size_t)n * DI + kk*32 + lg*8;
            short8 bf;
            #pragma unroll
            for (int j = 0; j < 8; ++j) bf[j] = (short)f2b(wp[j]);
            const short8 af = *(const short8*)(zfin + l15 * ZH_STR + kk*32 + lg*8);
            acc = __builtin_amdgcn_mfma_f32_16x16x32_bf16(af, bf, acc, 0, 0, 0);
        }
        #pragma unroll
        for (int r = 0; r < 4; ++r) {
            int t = lg * 4 + r;
            out[(size_t)(t0 + t) * DM + n] = acc[r] + bias;
        }
    }
}

// =======================================================================
// v1: round-3-proven fallback (256 blocks, CHUNK=32, RING=8, LAG=6, 413us)
// aggv layout: [RING1][NBLK1][DS][2] u64 (2 MB); cons at +2MB, 128B stride.
// =======================================================================
__global__ __launch_bounds__(NTHR, 2)
void implicit_v1(const float* __restrict__ x,
                 const float* __restrict__ f_w,   const float* __restrict__ f_b,
                 const float* __restrict__ lam_w, const float* __restrict__ lam_b,
                 const float* __restrict__ u_w,   const float* __restrict__ u_b,
                 const float* __restrict__ out_w, const float* __restrict__ out_b,
                 float* __restrict__ out,         u64* __restrict__ aggv,
                 int* __restrict__ cons)
{
    extern __shared__ unsigned char smem_raw[];
    unsigned short* w1  = (unsigned short*)(smem_raw + V1_OFF_W1);
    unsigned short* w2  = (unsigned short*)(smem_raw + V1_OFF_W2);
    unsigned short* zhA = (unsigned short*)(smem_raw + V1_OFF_ZHA);
    unsigned short* zhB = (unsigned short*)(smem_raw + V1_OFF_ZHB);
    unsigned short* xs  = (unsigned short*)(smem_raw + V1_OFF_XS);
    float* lamL = (float*)(smem_raw + V1_OFF_LAM);
    float* uL   = (float*)(smem_raw + V1_OFF_U);
    float* xlam = (float*)(smem_raw + V1_OFF_XLAM);
    float* xu   = (float*)(smem_raw + V1_OFF_XU);
    float* xf   = (float*)(smem_raw + V1_OFF_XF);

    const int b    = blockIdx.x;
    const int tid  = threadIdx.x;
    const int wid  = tid >> 6;
    const int lane = tid & 63;
    const int l15  = lane & 15;
    const int lg   = lane >> 4;
    const int t0   = b * CHUNK1;

    for (int i = tid; i < CHUNK1 * DM; i += NTHR) {
        int t = i >> 10, k = i & (DM - 1);
        xs[t * XS_STR + k] = f2b(x[(size_t)(t0 + t) * DM + k]);
    }
    __syncthreads();

    for (int half = 0; half < 2; ++half) {
        int nt = wid + 8 * half;
        int n  = nt * 16 + l15;
        const float* wrow; float bias;
        if (n < 64)       { wrow = lam_w + (size_t)n        * (DI + DM) + DI;             bias = lam_b[n]; }
        else if (n < 128) { wrow = u_w   + (size_t)(n - 64) * (DI + DM) + DI;             bias = u_b[n - 64]; }
        else              { wrow = f_w   + (size_t)(n - 128) * (DI + DS + DM) + (DI + DS); bias = f_b[n - 128]; }

        floatx4 acc[2] = {{0.f,0.f,0.f,0.f},{0.f,0.f,0.f,0.f}};
        for (int kk = 0; kk < DM / 32; ++kk) {
            const float* wp = wrow + kk * 32 + lg * 8;
            short8 bf;
            #pragma unroll
            for (int j = 0; j < 8; ++j) bf[j] = (short)f2b(wp[j]);
            #pragma unroll
            for (int mt = 0; mt < 2; ++mt) {
                const short8 af = *(const short8*)(xs + (mt*16 + l15) * XS_STR + kk * 32 + lg * 8);
                acc[mt] = __builtin_amdgcn_mfma_f32_16x16x32_bf16(af, bf, acc[mt], 0, 0, 0);
            }
        }
        #pragma unroll
        for (int mt = 0; mt < 2; ++mt)
            #pragma unroll
            for (int r = 0; r < 4; ++r) {
                int t = mt * 16 + lg * 4 + r;
                float v = acc[mt][r] + bias;
                if (n < 64)       xlam[t * DS + n] = v;
                else if (n < 128) xu[t * DS + (n - 64)] = v;
                else              xf[t * DI + (n - 128)] = v;
            }
    }
    __syncthreads();

    for (int i = tid; i < 128 * DI; i += NTHR) {
        int n = i >> 7, k = i & 127;
        float v = (n < 64) ? lam_w[(size_t)n * (DI + DM) + k]
                           : u_w[(size_t)(n - 64) * (DI + DM) + k];
        w1[n * W1_STR + k] = f2b(v);
    }
    for (int i = tid; i < 128 * 192; i += NTHR) {
        int n = i / 192, k = i - n * 192;
        w2[n * W2_STR + k] = f2b(f_w[(size_t)n * (DI + DS + DM) + k]);
    }
    __syncthreads();

    short8 w1f[4], w2f[6];
    #pragma unroll
    for (int kk = 0; kk < 4; ++kk)
        w1f[kk] = *(const short8*)(w1 + (wid*16 + l15) * W1_STR + kk*32 + lg*8);
    #pragma unroll
    for (int kk = 0; kk < 6; ++kk)
        w2f[kk] = *(const short8*)(w2 + (wid*16 + l15) * W2_STR + kk*32 + lg*8);
    __syncthreads();

    for (int i = tid; i < 2 * CHUNK1 * ZH_STR; i += NTHR) zhA[i] = 0;
    __syncthreads();

    for (int it = 0; it < NIT; ++it) {
        const int slot = it & (RING1 - 1);
        unsigned short* cur = (it & 1) ? zhB : zhA;
        unsigned short* nxt = (it & 1) ? zhA : zhB;

        u64 pa0 = 0, pa1 = 0, pb0 = 0, pb1 = 0;
        const u64 *l1 = 0, *l2 = 0;
        if (wid == 1 && b >= 1 && it >= LAG1) {
            const int pslot = (it - LAG1) & (RING1 - 1);
            l1 = aggv + (((size_t)pslot * NBLK1 + (b - 1)) * DS + lane) * 2;
            pa0 = __hip_atomic_load(&l1[0], __ATOMIC_RELAXED, __HIP_MEMORY_SCOPE_AGENT);
            pa1 = __hip_atomic_load(&l1[1], __ATOMIC_RELAXED, __HIP_MEMORY_SCOPE_AGENT);
            if (b >= 2) {
                l2 = aggv + (((size_t)pslot * NBLK1 + (b - 2)) * DS + lane) * 2;
                pb0 = __hip_atomic_load(&l2[0], __ATOMIC_RELAXED, __HIP_MEMORY_SCOPE_AGENT);
                pb1 = __hip_atomic_load(&l2[1], __ATOMIC_RELAXED, __HIP_MEMORY_SCOPE_AGENT);
            }
        }

        {
            floatx4 acc[2] = {{0.f,0.f,0.f,0.f},{0.f,0.f,0.f,0.f}};
            #pragma unroll
            for (int kk = 0; kk < 4; ++kk)
                #pragma unroll
                for (int mt = 0; mt < 2; ++mt) {
                    const short8 af = *(const short8*)(cur + (mt*16 + l15) * ZH_STR + kk*32 + lg*8);
                    acc[mt] = __builtin_amdgcn_mfma_f32_16x16x32_bf16(af, w1f[kk], acc[mt], 0, 0, 0);
                }
            const int n = wid * 16 + l15;
            #pragma unroll
            for (int mt = 0; mt < 2; ++mt)
                #pragma unroll
                for (int r = 0; r < 4; ++r) {
                    int t = mt*16 + lg*4 + r;
                    if (n < 64) lamL[t*DS + n] = sigmoidf_(acc[mt][r] + xlam[t*DS + n]);
                    else        uL[t*DS + (n - 64)] = acc[mt][r] + xu[t*DS + (n - 64)];
                }
        }
        __syncthreads();

        floatx4 acc2[2] = {{0.f,0.f,0.f,0.f},{0.f,0.f,0.f,0.f}};

        if (wid == 0) {
            float L = 1.f, H = 0.f;
            #pragma unroll 8
            for (int t = 0; t < CHUNK1; ++t) {
                float lv = lamL[t*DS + lane], uv = uL[t*DS + lane];
                H = fmaf(lv, H, uv);
                L *= lv;
            }
            if (it >= RING1 && lane < WIN) {
                int j = b + 1 + lane;
                if (j < NBLK1) {
                    while (__hip_atomic_load(&cons[j * 32], __ATOMIC_RELAXED,
                                             __HIP_MEMORY_SCOPE_AGENT) < it - RING1 + LAG1 + 1)
                        __builtin_amdgcn_s_sleep(1);
                }
            }
            u64* line = aggv + (((size_t)slot * NBLK1 + b) * DS + lane) * 2;
            VS vL, vH;
            vL.p.v = L; vL.p.st = it + 1;
            vH.p.v = H; vH.p.st = it + 1;
            __hip_atomic_store(&line[0], vL.u, __ATOMIC_RELAXED, __HIP_MEMORY_SCOPE_AGENT);
            __hip_atomic_store(&line[1], vH.u, __ATOMIC_RELAXED, __HIP_MEMORY_SCOPE_AGENT);
        } else if (wid == 1) {
            float h = 0.f;
            if (b >= 1 && it >= LAG1) {
                const int est = it - LAG1 + 1;
                VS aL, aH, bH;
                aL.u = pa0; aH.u = pa1; bH.u = pb1;
                bool ok = (aL.p.st == est) && (aH.p.st == est);
                if (b >= 2) { VS bL; bL.u = pb0;
                              ok = ok && (bL.p.st == est) && (bH.p.st == est); }
                while (!ok) {
                    __builtin_amdgcn_s_sleep(1);
                    aL.u = __hip_atomic_load(&l1[0], __ATOMIC_RELAXED, __HIP_MEMORY_SCOPE_AGENT);
                    aH.u = __hip_atomic_load(&l1[1], __ATOMIC_RELAXED, __HIP_MEMORY_SCOPE_AGENT);
                    ok = (aL.p.st == est) && (aH.p.st == est);
                    if (b >= 2) {
                        VS bL;
                        bL.u = __hip_atomic_load(&l2[0], __ATOMIC_RELAXED, __HIP_MEMORY_SCOPE_AGENT);
                        bH.u = __hip_atomic_load(&l2[1], __ATOMIC_RELAXED, __HIP_MEMORY_SCOPE_AGENT);
                        ok = ok && (bL.p.st == est) && (bH.p.st == est);
                    }
                }
                h = aH.p.v;
                if (b >= 2) h = fmaf(aL.p.v, bH.p.v, h);
            }
            #pragma unroll 8
            for (int t = 0; t < CHUNK1; ++t) {
                cur[t * ZH_STR + DI + lane] = f2b(h);
                h = fmaf(lamL[t*DS + lane], h, uL[t*DS + lane]);
            }
            drain_vm();
            if (lane == 0)
                __hip_atomic_store(&cons[b * 32], it + 1,
                                   __ATOMIC_RELAXED, __HIP_MEMORY_SCOPE_AGENT);
        } else {
            #pragma unroll
            for (int kk = 0; kk < 4; ++kk)
                #pragma unroll
                for (int mt = 0; mt < 2; ++mt) {
                    const short8 af = *(const short8*)(cur + (mt*16 + l15) * ZH_STR + kk*32 + lg*8);
                    acc2[mt] = __builtin_amdgcn_mfma_f32_16x16x32_bf16(af, w2f[kk], acc2[mt], 0, 0, 0);
                }
        }
        __syncthreads();

        if (wid <= 1) {
            #pragma unroll
            for (int kk = 0; kk < 4; ++kk)
                #pragma unroll
                for (int mt = 0; mt < 2; ++mt) {
                    const short8 af = *(const short8*)(cur + (mt*16 + l15) * ZH_STR + kk*32 + lg*8);
                    acc2[mt] = __builtin_amdgcn_mfma_f32_16x16x32_bf16(af, w2f[kk], acc2[mt], 0, 0, 0);
                }
        }
        #pragma unroll
        for (int kk = 4; kk < 6; ++kk)
            #pragma unroll
            for (int mt = 0; mt < 2; ++mt) {
                const short8 af = *(const short8*)(cur + (mt*16 + l15) * ZH_STR + kk*32 + lg*8);
                acc2[mt] = __builtin_amdgcn_mfma_f32_16x16x32_bf16(af, w2f[kk], acc2[mt], 0, 0, 0);
            }
        {
            const int d = wid * 16 + l15;
            #pragma unroll
            for (int mt = 0; mt < 2; ++mt)
                #pragma unroll
                for (int r = 0; r < 4; ++r) {
                    int t = mt*16 + lg*4 + r;
                    float v = acc2[mt][r] + xf[t*DI + d];
                    nxt[t * ZH_STR + d] = f2b(v * sigmoidf_(v));
                }
        }
        __syncthreads();
    }

    unsigned short* zfin = (NIT & 1) ? zhB : zhA;
    for (int q = 0; q < 8; ++q) {
        int nt = wid * 8 + q;
        int n  = nt * 16 + l15;
        float bias = out_b[n];
        floatx4 acc[2] = {{0.f,0.f,0.f,0.f},{0.f,0.f,0.f,0.f}};
        #pragma unroll
        for (int kk = 0; kk < 4; ++kk) {
            const float* wp = out_w + (size_t)n * DI + kk*32 + lg*8;
            short8 bf;
            #pragma unroll
            for (int j = 0; j < 8; ++j) bf[j] = (short)f2b(wp[j]);
            #pragma unroll
            for (int mt = 0; mt < 2; ++mt) {
                const short8 af = *(const short8*)(zfin + (mt*16 + l15) * ZH_STR + kk*32 + lg*8);
                acc[mt] = __builtin_amdgcn_mfma_f32_16x16x32_bf16(af, bf, acc[mt], 0, 0, 0);
            }
        }
        #pragma unroll
        for (int mt = 0; mt < 2; ++mt)
            #pragma unroll
            for (int r = 0; r < 4; ++r) {
                int t = mt*16 + lg*4 + r;
                out[(size_t)(t0 + t) * DM + n] = acc[mt][r] + bias;
            }
    }
}

extern "C" void kernel_launch(void* const* d_in, const int* in_sizes, int n_in,
                              void* d_out, int out_size, void* d_ws, size_t ws_size,
                              hipStream_t stream) {
    (void)in_sizes; (void)n_in; (void)out_size; (void)ws_size;
    const float* x     = (const float*)d_in[0];
    const float* f_w   = (const float*)d_in[1];
    const float* f_b   = (const float*)d_in[2];
    const float* lam_w = (const float*)d_in[3];
    const float* lam_b = (const float*)d_in[4];
    const float* u_w   = (const float*)d_in[5];
    const float* u_b   = (const float*)d_in[6];
    const float* out_w = (const float*)d_in[7];
    const float* out_b = (const float*)d_in[8];
    float* out = (float*)d_out;

    // workspace (re-poisoned 0xAA before every launch): aggv 2 MB @0, cons @+2MB.
    // Total footprint = 2 MB + 32 KB for BOTH kernels (= previously proven usage).
    char* ws = (char*)d_ws;
    u64* aggv = (u64*)ws;
    int* cons = (int*)(ws + (size_t)2 * 1024 * 1024);

    hipFuncSetAttribute((const void*)implicit_v2,
                        hipFuncAttributeMaxDynamicSharedMemorySize, V2_LDS);
    hipFuncSetAttribute((const void*)implicit_v1,
                        hipFuncAttributeMaxDynamicSharedMemorySize, V1_LDS);

    // Decide once: can v2 co-locate 2 blocks/CU? (pure host query, capture-safe)
    static int use_v2 = -1;
    if (use_v2 < 0) {
        int nb = 0;
        hipError_t e = hipOccupancyMaxActiveBlocksPerMultiprocessor(
            &nb, (const void*)implicit_v2, NTHR, (size_t)V2_LDS);
        use_v2 = (e == hipSuccess && nb >= 2) ? 1 : 0;
    }

    void* args[] = {(void*)&x, (void*)&f_w, (void*)&f_b, (void*)&lam_w, (void*)&lam_b,
                    (void*)&u_w, (void*)&u_b, (void*)&out_w, (void*)&out_b,
                    (void*)&out, (void*)&aggv, (void*)&cons};
    if (use_v2) {
        hipLaunchCooperativeKernel((const void*)implicit_v2, dim3(NBLK2), dim3(NTHR),
                                   args, V2_LDS, stream);
    } else {
        hipLaunchCooperativeKernel((const void*)implicit_v1, dim3(NBLK1), dim3(NTHR),
                                   args, V1_LDS, stream);
    }
}